// Round 25
// baseline (97.108 us; speedup 1.0000x reference)
//
#include <hip/hip_runtime.h>
#include <hip/hip_bf16.h>

#define NB 16
#define DMODEL 1024
#define HALFD 512
#define PNUM 4096
#define PLEN 32
#define SEQ 2048
#define SIM 64
#define NPATCH 64
#define NROWS (NB*SEQ)        // 32768 sequence rows
#define MROWS (NB*NPATCH)     // 1024 (b,p) rows
#define KDIM (PLEN*HALFD)     // 16384
#define NCOPY 512
#define OUT0 ((size_t)NB*SEQ*DMODEL)

typedef __attribute__((ext_vector_type(8))) short s8v;          // 8 bf16 (4 VGPR)
typedef __attribute__((ext_vector_type(4))) float f32x4;
typedef __attribute__((ext_vector_type(8))) unsigned short ush8;
typedef unsigned long long u64;

__device__ __forceinline__ unsigned short f2bf(float f) {
    __hip_bfloat16 h = __float2bfloat16(f);
    return *reinterpret_cast<unsigned short*>(&h);
}
__device__ __forceinline__ u64 umax64(u64 a, u64 b) { return a > b ? a : b; }
__device__ __forceinline__ u64 umin64(u64 a, u64 b) { return a < b ? a : b; }
__device__ __forceinline__ u64 clean6(u64 v, int lane) {
    #pragma unroll
    for (int j = 32; j; j >>= 1) {
        u64 o = __shfl_xor(v, j);
        v = ((lane & j) == 0) ? umax64(v, o) : umin64(v, o);
    }
    return v;
}

// ---- D1: fw pack (0..255) | rw pack (256..271) ----
__global__ __launch_bounds__(256) void k_pack(
        const float* __restrict__ fw, const float* __restrict__ rw,
        unsigned short* __restrict__ fwT, unsigned short* __restrict__ rwf) {
    __shared__ float tile[64][68];
    int bid = blockIdx.x, t = threadIdx.x;
    int lane = t & 63;
    if (bid < 256) {
        int k0 = bid * 64;
        int i = t >> 2;
        #pragma unroll
        for (int q = 0; q < 4; ++q) {
            int c = (t & 3) + q*4;
            float4 v = *reinterpret_cast<const float4*>(fw + (size_t)(k0 + i)*SIM + c*4);
            *reinterpret_cast<float4*>(&tile[i][c*4]) = v;
        }
        __syncthreads();
        #pragma unroll
        for (int c2 = 0; c2 < 2; ++c2) {
            int e = c2*256 + t;
            int kl = e >> 8, fn = (e >> 6) & 3, l = e & 63;
            int kk0 = kl*32 + ((l >> 4) * 8), n = fn*16 + (l & 15);
            ush8 hv;
            #pragma unroll
            for (int j = 0; j < 8; ++j) hv[j] = f2bf(tile[kk0 + j][n]);
            size_t dst = ((size_t)((2*bid + kl)*4 + fn)*64 + l)*8;
            *reinterpret_cast<ush8*>(fwT + dst) = hv;
        }
    } else {
        int q = t >> 6;
        int idx = (bid - 256)*4 + q;           // 0..63 = (ks,fn)
        int ks = idx >> 5, fn = idx & 31;
        int ml = lane & 15, kg = lane >> 4;
        ush8 hv;
        #pragma unroll
        for (int j = 0; j < 8; ++j)
            hv[j] = f2bf(rw[(size_t)(ks*32 + kg*8 + j)*HALFD + fn*16 + ml]);
        size_t dst = ((size_t)idx*64 + lane)*8;
        *reinterpret_cast<ush8*>(rwf + dst) = hv;
    }
}

// ---- D2: logits MFMA (0..16*nks-1) | topk self-contained (next 512) ----
__global__ __launch_bounds__(256) void k_mid(
        const float* __restrict__ src, const unsigned short* __restrict__ fwT,
        const float* __restrict__ pool,
        const float* __restrict__ gp_w, const float* __restrict__ gp_b,
        float* __restrict__ part, u64* __restrict__ cand, int nks) {
    int t = threadIdx.x, lane = t & 63, w = t >> 6;
    int bid = blockIdx.x;
    int NL = 16*nks;
    if (bid >= NL) {
        // ---- topk role: own gp means + own lowp + scores + wave-reg bitonic ----
        __shared__ struct { double gpm[513]; double lowp[PLEN]; u64 wl[4][64]; } u;
        int tb = bid - NL;
        int p = tb >> 3, q = tb & 7;
        for (int h = t; h < HALFD; h += 256) {
            double s = 0.0;
            #pragma unroll
            for (int j = 0; j < 10; ++j) s += (double)gp_w[h*10 + j];
            u.gpm[h] = s / 10.0;
        }
        if (t == 0) {
            double sb = 0.0;
            #pragma unroll
            for (int j = 0; j < 10; ++j) sb += (double)gp_b[j];
            u.gpm[512] = sb / 10.0;
        }
        __syncthreads();
        {
            const double* g0 = u.gpm + lane*4;
            const double* g1 = u.gpm + 256 + lane*4;
            #pragma unroll
            for (int rr = 0; rr < 8; ++rr) {
                int r = w*8 + rr;
                const float4* s4 = reinterpret_cast<const float4*>(src + (size_t)(p*PLEN + r)*DMODEL);
                float4 x0 = s4[128 + lane], x1 = s4[192 + lane];
                double d = (double)x0.x*g0[0] + (double)x0.y*g0[1] + (double)x0.z*g0[2] + (double)x0.w*g0[3]
                         + (double)x1.x*g1[0] + (double)x1.y*g1[1] + (double)x1.z*g1[2] + (double)x1.w*g1[3];
                #pragma unroll
                for (int o = 32; o; o >>= 1) d += __shfl_xor(d, o);
                if (lane == 0) u.lowp[r] = d + u.gpm[512];
            }
        }
        __syncthreads();
        u64 v[2];
        #pragma unroll
        for (int cc = 0; cc < 2; ++cc) {
            int n = q*512 + (w*2 + cc)*64 + lane;
            const float4* p4 = reinterpret_cast<const float4*>(pool + (size_t)n*PLEN);
            double s = 0.0;
            #pragma unroll
            for (int r2 = 0; r2 < 8; ++r2) {
                float4 vv = p4[r2];
                s += (double)vv.x*u.lowp[r2*4] + (double)vv.y*u.lowp[r2*4+1]
                   + (double)vv.z*u.lowp[r2*4+2] + (double)vv.w*u.lowp[r2*4+3];
            }
            u64 ub = (u64)__double_as_longlong(s);
            u64 okey = ub ^ (((u64)((long long)ub >> 63)) | 0x8000000000000000ULL);
            v[cc] = (okey & ~0xFFFULL) | (u64)(0xFFF - n);
        }
        #pragma unroll
        for (int kk = 2; kk <= 64; kk <<= 1) {
            #pragma unroll
            for (int j = kk >> 1; j; j >>= 1) {
                #pragma unroll
                for (int cc = 0; cc < 2; ++cc) {
                    u64 o = __shfl_xor(v[cc], j);
                    bool keepMax = ((lane & kk) == 0) == ((lane & j) == 0);
                    v[cc] = keepMax ? umax64(v[cc], o) : umin64(v[cc], o);
                }
            }
        }
        u64 rb2 = __shfl(v[1], 63 - lane);
        u64 m = umax64(v[0], rb2);
        m = clean6(m, lane);
        u.wl[w][lane] = m;
        __syncthreads();
        if (w == 0) {
            u64 a = umax64(u.wl[0][lane], u.wl[1][63 - lane]); a = clean6(a, lane);
            u64 b = umax64(u.wl[2][lane], u.wl[3][63 - lane]); b = clean6(b, lane);
            u64 r2 = __shfl(b, 63 - lane);
            u64 f = umax64(a, r2); f = clean6(f, lane);
            cand[(size_t)(p*8 + q)*SIM + lane] = f;
        }
        return;
    }
    int mt = bid / nks, ks = bid - mt*nks;
    int kchunk = KDIM / nks, nstep = kchunk >> 6;
    int r0 = mt*64;
    int ml = lane & 15, kg = lane >> 4;
    int Rrow = r0 + w*16 + ml;
    int bb = Rrow >> 6, prow = Rrow & 63;
    const float* xrow = src + ((size_t)(bb*SEQ + prow*PLEN))*DMODEL + HALFD;
    int kblk_base = (ks*kchunk) >> 5;
    f32x4 acc[4] = {};
    for (int step = 0; step < nstep; ++step) {
        int k0 = ks*kchunk + step*64;
        int l = k0 >> 9, h0 = k0 & 511;          // 64-chunk never crosses l
        const float* ap = xrow + (size_t)l*DMODEL + h0 + kg*8;
        float4 va0 = *reinterpret_cast<const float4*>(ap);
        float4 va1 = *reinterpret_cast<const float4*>(ap + 4);
        float4 vb0 = *reinterpret_cast<const float4*>(ap + 32);
        float4 vb1 = *reinterpret_cast<const float4*>(ap + 36);
        s8v ah0, ah1;
        float fa[8] = {va0.x,va0.y,va0.z,va0.w,va1.x,va1.y,va1.z,va1.w};
        float fbv[8] = {vb0.x,vb0.y,vb0.z,vb0.w,vb1.x,vb1.y,vb1.z,vb1.w};
        #pragma unroll
        for (int j = 0; j < 8; ++j) {
            ah0[j] = (short)f2bf(fa[j]);
            ah1[j] = (short)f2bf(fbv[j]);
        }
        int kblk0 = kblk_base + step*2;
        #pragma unroll
        for (int fn = 0; fn < 4; ++fn) {
            size_t off0 = ((size_t)(kblk0*4 + fn)*64 + lane)*8;
            size_t off1 = ((size_t)((kblk0+1)*4 + fn)*64 + lane)*8;
            s8v bh0 = *reinterpret_cast<const s8v*>(fwT + off0);
            s8v bh1 = *reinterpret_cast<const s8v*>(fwT + off1);
            acc[fn] = __builtin_amdgcn_mfma_f32_16x16x32_bf16(ah0, bh0, acc[fn], 0, 0, 0);
            acc[fn] = __builtin_amdgcn_mfma_f32_16x16x32_bf16(ah1, bh1, acc[fn], 0, 0, 0);
        }
    }
    float* pout = part + (size_t)(mt*nks + ks)*4096;
    #pragma unroll
    for (int fn = 0; fn < 4; ++fn)
        #pragma unroll
        for (int r = 0; r < 4; ++r)
            pout[(w*16 + kg*4 + r)*64 + fn*16 + ml] = acc[fn][r];
}

// ---- D3: out (0..1023) FIRST | copy (1024..1535) LAST ----
union OutShared {
    struct { float A_T[SIM][36]; float routeS[64]; int selS[64]; float psum[4][64]; } a;  // ~11 KB
    float xpose[16][516];                                                                 // 33 KB
};
__global__ __launch_bounds__(256) void k_out(
        const float* __restrict__ part, const float* __restrict__ fb,
        const u64* __restrict__ cand, const float* __restrict__ pool,
        const unsigned short* __restrict__ rwf, const float* __restrict__ rb,
        const float* __restrict__ src, float* __restrict__ out,
        float* __restrict__ pad, int nks) {
    __shared__ OutShared u;
    int t = threadIdx.x, lane = t & 63, w = t >> 6;
    if (blockIdx.x >= MROWS) {
        // ---- copy role: out[:, :512] = src[:, :512] ----
        int cb = blockIdx.x - MROWS;
        size_t total = (size_t)NROWS * 128;
        const float4* s4 = reinterpret_cast<const float4*>(src);
        float4* o4 = reinterpret_cast<float4*>(out);
        for (size_t idx = (size_t)cb*256 + t; idx < total; idx += (size_t)NCOPY*256) {
            size_t r = idx >> 7, c = idx & 127;
            o4[r*256 + c] = s4[r*256 + c];
        }
        return;
    }
    int row = blockIdx.x;                    // b*64+p
    int b = row >> 6, p = row & 63;
    int kpw = nks >> 2;
    {
        float v = 0.f;
        for (int kq = 0; kq < kpw; ++kq) {
            int ks = w*kpw + kq;
            v += part[(size_t)(b*nks + ks)*4096 + p*64 + lane];
        }
        u.a.psum[w][lane] = v;
    }
    __syncthreads();
    if (w == 0) {
        float v = u.a.psum[0][lane] + u.a.psum[1][lane] + u.a.psum[2][lane] + u.a.psum[3][lane] + fb[lane];
        float m = v;
        #pragma unroll
        for (int o = 32; o; o >>= 1) m = fmaxf(m, __shfl_xor(m, o));
        float e = expf(v - m);
        float sum = e;
        #pragma unroll
        for (int o = 32; o; o >>= 1) sum += __shfl_xor(sum, o);
        u.a.routeS[lane] = e / sum;
    } else if (w == 1) {
        const u64* c = cand + (size_t)p*8*SIM;
        u64 a = umax64(c[lane],         c[1*SIM + 63 - lane]); a = clean6(a, lane);
        u64 bq = umax64(c[2*SIM + lane], c[3*SIM + 63 - lane]); bq = clean6(bq, lane);
        u64 d = umax64(c[4*SIM + lane], c[5*SIM + 63 - lane]); d = clean6(d, lane);
        u64 e = umax64(c[6*SIM + lane], c[7*SIM + 63 - lane]); e = clean6(e, lane);
        u64 ab = umax64(a, __shfl(bq, 63 - lane)); ab = clean6(ab, lane);
        u64 de = umax64(d, __shfl(e, 63 - lane)); de = clean6(de, lane);
        u64 f  = umax64(ab, __shfl(de, 63 - lane)); f = clean6(f, lane);
        u.a.selS[lane] = 0xFFF - (int)(f & 0xFFFULL);
    }
    __syncthreads();
    #pragma unroll
    for (int q = 0; q < 8; ++q) {            // A_T[s][l] = route[s]*pool[sel[s]][l]
        int e = t + q*256;
        int s = e >> 5, l = e & 31;
        u.a.A_T[s][l] = u.a.routeS[s] * pool[(size_t)u.a.selS[s]*PLEN + l];
    }
    __syncthreads();
    if (t < 32) {                            // padding row-sum
        float ps = 0.f;
        #pragma unroll
        for (int s = 0; s < 64; ++s) ps += u.a.A_T[s][t];
        pad[(size_t)b*2*SEQ + SEQ + p*PLEN + t] = ps;
    } else if (t < 64) {
        pad[(size_t)b*2*SEQ + p*PLEN + (t - 32)] = 0.f;
    }
    int ml = lane & 15, kg = lane >> 4;
    s8v ah[2][2];                            // [mt][ks], plain bf16
    #pragma unroll
    for (int mt = 0; mt < 2; ++mt)
        #pragma unroll
        for (int ks = 0; ks < 2; ++ks) {
            #pragma unroll
            for (int j = 0; j < 8; ++j)
                ah[mt][ks][j] = (short)f2bf(u.a.A_T[ks*32 + kg*8 + j][mt*16 + ml]);
        }
    f32x4 accA[8], accB[8];
    #pragma unroll
    for (int nt = 0; nt < 8; ++nt) {
        int fng = w*8 + nt;
        f32x4 acc0 = {}, acc1 = {};
        #pragma unroll
        for (int ks = 0; ks < 2; ++ks) {
            size_t off = ((size_t)(ks*32 + fng)*64 + lane)*8;
            s8v bh = *reinterpret_cast<const s8v*>(rwf + off);
            acc0 = __builtin_amdgcn_mfma_f32_16x16x32_bf16(ah[0][ks], bh, acc0, 0, 0, 0);
            acc1 = __builtin_amdgcn_mfma_f32_16x16x32_bf16(ah[1][ks], bh, acc1, 0, 0, 0);
        }
        float bias = rb[fng*16 + ml];
        #pragma unroll
        for (int r = 0; r < 4; ++r) { acc0[r] += bias; acc1[r] += bias; }
        accA[nt] = acc0; accB[nt] = acc1;
    }
    size_t orow0 = ((size_t)(b*SEQ + p*PLEN))*DMODEL + HALFD;
    #pragma unroll
    for (int mt = 0; mt < 2; ++mt) {
        __syncthreads();
        #pragma unroll
        for (int nt = 0; nt < 8; ++nt) {
            f32x4 a = (mt == 0) ? accA[nt] : accB[nt];
            #pragma unroll
            for (int r = 0; r < 4; ++r)
                u.xpose[kg*4 + r][w*128 + nt*16 + ml] = a[r];
        }
        __syncthreads();
        #pragma unroll
        for (int q = 0; q < 8; ++q) {
            int e = q*256 + t;               // 16 rows x 128 float4
            int rr = e >> 7, c4 = e & 127;
            float4 v = *reinterpret_cast<float4*>(&u.xpose[rr][c4*4]);
            *reinterpret_cast<float4*>(out + orow0 + (size_t)(mt*16 + rr)*DMODEL + c4*4) = v;
        }
    }
}

static const void* by_size(void* const* d_in, const int* in_sizes, int n_in,
                           int want, int fallback) {
    for (int i = 0; i < n_in; ++i) if (in_sizes[i] == want) return d_in[i];
    return d_in[fallback];
}

extern "C" void kernel_launch(void* const* d_in, const int* in_sizes, int n_in,
                              void* d_out, int out_size, void* d_ws, size_t ws_size,
                              hipStream_t stream) {
    const float* src  = (const float*)by_size(d_in, in_sizes, n_in, NB*SEQ*DMODEL, 0);
    const float* pool = (const float*)by_size(d_in, in_sizes, n_in, PNUM*PLEN, 1);
    const float* fw   = (const float*)by_size(d_in, in_sizes, n_in, KDIM*SIM, 2);
    const float* fb   = (const float*)by_size(d_in, in_sizes, n_in, SIM, 3);
    const float* rw   = (const float*)by_size(d_in, in_sizes, n_in, SIM*HALFD, 4);
    const float* rb   = (const float*)by_size(d_in, in_sizes, n_in, HALFD, 5);
    const float* gpw  = (const float*)by_size(d_in, in_sizes, n_in, HALFD*10, 6);
    const float* gpb  = (const float*)by_size(d_in, in_sizes, n_in, 10, 7);
    float* out = (float*)d_out;
    float* pad = out + OUT0;

    int nks = (ws_size >= (size_t)(16u << 20)) ? 32 : 8;

    unsigned short* fwT = (unsigned short*)d_ws;                        // 2 MB
    unsigned short* rwf = fwT + (size_t)SIM*KDIM;                       // 64 KB
    u64*   cand  = (u64*)(rwf + (size_t)SIM*HALFD);                     // 256 KB
    float* part  = (float*)(cand + (size_t)NPATCH*8*SIM);               // nks * 256 KB

    hipLaunchKernelGGL(k_pack, dim3(272),          dim3(256), 0, stream, fw, rw, fwT, rwf);
    hipLaunchKernelGGL(k_mid,  dim3(16*nks + 512), dim3(256), 0, stream,
                       src, fwT, pool, gpw, gpb, part, cand, nks);
    hipLaunchKernelGGL(k_out,  dim3(MROWS + NCOPY), dim3(256), 0, stream,
                       part, fb, cand, pool, rwf, rb, src, out, pad, nks);
}

// Round 26
// 84.307 us; speedup vs baseline: 1.1518x; 1.1518x over previous
//
#include <hip/hip_runtime.h>
#include <hip/hip_bf16.h>

#define NB 16
#define DMODEL 1024
#define HALFD 512
#define PNUM 4096
#define PLEN 32
#define SEQ 2048
#define SIM 64
#define NPATCH 64
#define NROWS (NB*SEQ)        // 32768 sequence rows
#define MROWS (NB*NPATCH)     // 1024 (b,p) rows
#define KDIM (PLEN*HALFD)     // 16384
#define NCOPY 512
#define OUT0 ((size_t)NB*SEQ*DMODEL)

typedef __attribute__((ext_vector_type(8))) short s8v;          // 8 bf16 (4 VGPR)
typedef __attribute__((ext_vector_type(4))) float f32x4;
typedef __attribute__((ext_vector_type(8))) unsigned short ush8;
typedef unsigned long long u64;

__device__ __forceinline__ unsigned short f2bf(float f) {
    __hip_bfloat16 h = __float2bfloat16(f);
    return *reinterpret_cast<unsigned short*>(&h);
}
__device__ __forceinline__ u64 umax64(u64 a, u64 b) { return a > b ? a : b; }
__device__ __forceinline__ u64 umin64(u64 a, u64 b) { return a < b ? a : b; }
__device__ __forceinline__ u64 clean6(u64 v, int lane) {
    #pragma unroll
    for (int j = 32; j; j >>= 1) {
        u64 o = __shfl_xor(v, j);
        v = ((lane & j) == 0) ? umax64(v, o) : umin64(v, o);
    }
    return v;
}

// ---- D1: fw pack (0..255) | rw pack (256..271) ----
__global__ __launch_bounds__(256) void k_pack(
        const float* __restrict__ fw, const float* __restrict__ rw,
        unsigned short* __restrict__ fwT, unsigned short* __restrict__ rwf) {
    __shared__ float tile[64][68];
    int bid = blockIdx.x, t = threadIdx.x;
    int lane = t & 63;
    if (bid < 256) {
        int k0 = bid * 64;
        int i = t >> 2;
        #pragma unroll
        for (int q = 0; q < 4; ++q) {
            int c = (t & 3) + q*4;
            float4 v = *reinterpret_cast<const float4*>(fw + (size_t)(k0 + i)*SIM + c*4);
            *reinterpret_cast<float4*>(&tile[i][c*4]) = v;
        }
        __syncthreads();
        #pragma unroll
        for (int c2 = 0; c2 < 2; ++c2) {
            int e = c2*256 + t;
            int kl = e >> 8, fn = (e >> 6) & 3, l = e & 63;
            int kk0 = kl*32 + ((l >> 4) * 8), n = fn*16 + (l & 15);
            ush8 hv;
            #pragma unroll
            for (int j = 0; j < 8; ++j) hv[j] = f2bf(tile[kk0 + j][n]);
            size_t dst = ((size_t)((2*bid + kl)*4 + fn)*64 + l)*8;
            *reinterpret_cast<ush8*>(fwT + dst) = hv;
        }
    } else {
        int q = t >> 6;
        int idx = (bid - 256)*4 + q;           // 0..63 = (ks,fn)
        int ks = idx >> 5, fn = idx & 31;
        int ml = lane & 15, kg = lane >> 4;
        ush8 hv;
        #pragma unroll
        for (int j = 0; j < 8; ++j)
            hv[j] = f2bf(rw[(size_t)(ks*32 + kg*8 + j)*HALFD + fn*16 + ml]);
        size_t dst = ((size_t)idx*64 + lane)*8;
        *reinterpret_cast<ush8*>(rwf + dst) = hv;
    }
}

// ---- D2: logits MFMA (0..16*nks-1) | topk self-contained (next 512) ----
__global__ __launch_bounds__(256) void k_mid(
        const float* __restrict__ src, const unsigned short* __restrict__ fwT,
        const float* __restrict__ pool,
        const float* __restrict__ gp_w, const float* __restrict__ gp_b,
        float* __restrict__ part, u64* __restrict__ cand, int nks) {
    int t = threadIdx.x, lane = t & 63, w = t >> 6;
    int bid = blockIdx.x;
    int NL = 16*nks;
    if (bid >= NL) {
        // ---- topk role: own gp means + own lowp + scores + wave-reg bitonic ----
        __shared__ struct { double gpm[513]; double lowp[PLEN]; u64 wl[4][64]; } u;
        int tb = bid - NL;
        int p = tb >> 3, q = tb & 7;
        for (int h = t; h < HALFD; h += 256) {
            double s = 0.0;
            #pragma unroll
            for (int j = 0; j < 10; ++j) s += (double)gp_w[h*10 + j];
            u.gpm[h] = s / 10.0;
        }
        if (t == 0) {
            double sb = 0.0;
            #pragma unroll
            for (int j = 0; j < 10; ++j) sb += (double)gp_b[j];
            u.gpm[512] = sb / 10.0;
        }
        __syncthreads();
        {
            const double* g0 = u.gpm + lane*4;
            const double* g1 = u.gpm + 256 + lane*4;
            #pragma unroll
            for (int rr = 0; rr < 8; ++rr) {
                int r = w*8 + rr;
                const float4* s4 = reinterpret_cast<const float4*>(src + (size_t)(p*PLEN + r)*DMODEL);
                float4 x0 = s4[128 + lane], x1 = s4[192 + lane];
                double d = (double)x0.x*g0[0] + (double)x0.y*g0[1] + (double)x0.z*g0[2] + (double)x0.w*g0[3]
                         + (double)x1.x*g1[0] + (double)x1.y*g1[1] + (double)x1.z*g1[2] + (double)x1.w*g1[3];
                #pragma unroll
                for (int o = 32; o; o >>= 1) d += __shfl_xor(d, o);
                if (lane == 0) u.lowp[r] = d + u.gpm[512];
            }
        }
        __syncthreads();
        u64 v[2];
        #pragma unroll
        for (int cc = 0; cc < 2; ++cc) {
            int n = q*512 + (w*2 + cc)*64 + lane;
            const float4* p4 = reinterpret_cast<const float4*>(pool + (size_t)n*PLEN);
            double s = 0.0;
            #pragma unroll
            for (int r2 = 0; r2 < 8; ++r2) {
                float4 vv = p4[r2];
                s += (double)vv.x*u.lowp[r2*4] + (double)vv.y*u.lowp[r2*4+1]
                   + (double)vv.z*u.lowp[r2*4+2] + (double)vv.w*u.lowp[r2*4+3];
            }
            u64 ub = (u64)__double_as_longlong(s);
            u64 okey = ub ^ (((u64)((long long)ub >> 63)) | 0x8000000000000000ULL);
            v[cc] = (okey & ~0xFFFULL) | (u64)(0xFFF - n);
        }
        #pragma unroll
        for (int kk = 2; kk <= 64; kk <<= 1) {
            #pragma unroll
            for (int j = kk >> 1; j; j >>= 1) {
                #pragma unroll
                for (int cc = 0; cc < 2; ++cc) {
                    u64 o = __shfl_xor(v[cc], j);
                    bool keepMax = ((lane & kk) == 0) == ((lane & j) == 0);
                    v[cc] = keepMax ? umax64(v[cc], o) : umin64(v[cc], o);
                }
            }
        }
        u64 rb2 = __shfl(v[1], 63 - lane);
        u64 m = umax64(v[0], rb2);
        m = clean6(m, lane);
        u.wl[w][lane] = m;
        __syncthreads();
        if (w == 0) {
            u64 a = umax64(u.wl[0][lane], u.wl[1][63 - lane]); a = clean6(a, lane);
            u64 b = umax64(u.wl[2][lane], u.wl[3][63 - lane]); b = clean6(b, lane);
            u64 r2 = __shfl(b, 63 - lane);
            u64 f = umax64(a, r2); f = clean6(f, lane);
            cand[(size_t)(p*8 + q)*SIM + lane] = f;
        }
        return;
    }
    int mt = bid / nks, ks = bid - mt*nks;
    int kchunk = KDIM / nks, nstep = kchunk >> 6;
    int r0 = mt*64;
    int ml = lane & 15, kg = lane >> 4;
    int Rrow = r0 + w*16 + ml;
    int bb = Rrow >> 6, prow = Rrow & 63;
    const float* xrow = src + ((size_t)(bb*SEQ + prow*PLEN))*DMODEL + HALFD;
    int kblk_base = (ks*kchunk) >> 5;
    f32x4 acc[4] = {};
    for (int step = 0; step < nstep; ++step) {
        int k0 = ks*kchunk + step*64;
        int l = k0 >> 9, h0 = k0 & 511;          // 64-chunk never crosses l
        const float* ap = xrow + (size_t)l*DMODEL + h0 + kg*8;
        float4 va0 = *reinterpret_cast<const float4*>(ap);
        float4 va1 = *reinterpret_cast<const float4*>(ap + 4);
        float4 vb0 = *reinterpret_cast<const float4*>(ap + 32);
        float4 vb1 = *reinterpret_cast<const float4*>(ap + 36);
        s8v ah0, ah1;
        float fa[8] = {va0.x,va0.y,va0.z,va0.w,va1.x,va1.y,va1.z,va1.w};
        float fbv[8] = {vb0.x,vb0.y,vb0.z,vb0.w,vb1.x,vb1.y,vb1.z,vb1.w};
        #pragma unroll
        for (int j = 0; j < 8; ++j) {
            ah0[j] = (short)f2bf(fa[j]);
            ah1[j] = (short)f2bf(fbv[j]);
        }
        int kblk0 = kblk_base + step*2;
        #pragma unroll
        for (int fn = 0; fn < 4; ++fn) {
            size_t off0 = ((size_t)(kblk0*4 + fn)*64 + lane)*8;
            size_t off1 = ((size_t)((kblk0+1)*4 + fn)*64 + lane)*8;
            s8v bh0 = *reinterpret_cast<const s8v*>(fwT + off0);
            s8v bh1 = *reinterpret_cast<const s8v*>(fwT + off1);
            acc[fn] = __builtin_amdgcn_mfma_f32_16x16x32_bf16(ah0, bh0, acc[fn], 0, 0, 0);
            acc[fn] = __builtin_amdgcn_mfma_f32_16x16x32_bf16(ah1, bh1, acc[fn], 0, 0, 0);
        }
    }
    float* pout = part + (size_t)(mt*nks + ks)*4096;
    #pragma unroll
    for (int fn = 0; fn < 4; ++fn)
        #pragma unroll
        for (int r = 0; r < 4; ++r)
            pout[(w*16 + kg*4 + r)*64 + fn*16 + ml] = acc[fn][r];
}

// ---- D3: copy (0..511) | out (512..1535): psum + softmax | in-block merge + A build + MFMA + transposed stores ----
union OutShared {
    struct { float A_T[SIM][36]; float routeS[64]; int selS[64]; float psum[4][64]; } a;  // ~11 KB
    float xpose[16][516];                                                                 // 33 KB
};
__global__ __launch_bounds__(256) void k_out(
        const float* __restrict__ part, const float* __restrict__ fb,
        const u64* __restrict__ cand, const float* __restrict__ pool,
        const unsigned short* __restrict__ rwf, const float* __restrict__ rb,
        const float* __restrict__ src, float* __restrict__ out,
        float* __restrict__ pad, int nks) {
    __shared__ OutShared u;
    int t = threadIdx.x, lane = t & 63, w = t >> 6;
    if (blockIdx.x < NCOPY) {
        // ---- copy role: out[:, :512] = src[:, :512] ----
        int cb = blockIdx.x;
        size_t total = (size_t)NROWS * 128;
        const float4* s4 = reinterpret_cast<const float4*>(src);
        float4* o4 = reinterpret_cast<float4*>(out);
        for (size_t idx = (size_t)cb*256 + t; idx < total; idx += (size_t)NCOPY*256) {
            size_t r = idx >> 7, c = idx & 127;
            o4[r*256 + c] = s4[r*256 + c];
        }
        return;
    }
    int row = blockIdx.x - NCOPY;            // b*64+p
    int b = row >> 6, p = row & 63;
    int kpw = nks >> 2;
    {
        float v = 0.f;
        for (int kq = 0; kq < kpw; ++kq) {
            int ks = w*kpw + kq;
            v += part[(size_t)(b*nks + ks)*4096 + p*64 + lane];
        }
        u.a.psum[w][lane] = v;
    }
    __syncthreads();
    if (w == 0) {
        float v = u.a.psum[0][lane] + u.a.psum[1][lane] + u.a.psum[2][lane] + u.a.psum[3][lane] + fb[lane];
        float m = v;
        #pragma unroll
        for (int o = 32; o; o >>= 1) m = fmaxf(m, __shfl_xor(m, o));
        float e = expf(v - m);
        float sum = e;
        #pragma unroll
        for (int o = 32; o; o >>= 1) sum += __shfl_xor(sum, o);
        u.a.routeS[lane] = e / sum;
    } else if (w == 1) {
        const u64* c = cand + (size_t)p*8*SIM;
        u64 a = umax64(c[lane],         c[1*SIM + 63 - lane]); a = clean6(a, lane);
        u64 bq = umax64(c[2*SIM + lane], c[3*SIM + 63 - lane]); bq = clean6(bq, lane);
        u64 d = umax64(c[4*SIM + lane], c[5*SIM + 63 - lane]); d = clean6(d, lane);
        u64 e = umax64(c[6*SIM + lane], c[7*SIM + 63 - lane]); e = clean6(e, lane);
        u64 ab = umax64(a, __shfl(bq, 63 - lane)); ab = clean6(ab, lane);
        u64 de = umax64(d, __shfl(e, 63 - lane)); de = clean6(de, lane);
        u64 f  = umax64(ab, __shfl(de, 63 - lane)); f = clean6(f, lane);
        u.a.selS[lane] = 0xFFF - (int)(f & 0xFFFULL);
    }
    __syncthreads();
    #pragma unroll
    for (int q = 0; q < 8; ++q) {            // A_T[s][l] = route[s]*pool[sel[s]][l]
        int e = t + q*256;
        int s = e >> 5, l = e & 31;
        u.a.A_T[s][l] = u.a.routeS[s] * pool[(size_t)u.a.selS[s]*PLEN + l];
    }
    __syncthreads();
    if (t < 32) {                            // padding row-sum
        float ps = 0.f;
        #pragma unroll
        for (int s = 0; s < 64; ++s) ps += u.a.A_T[s][t];
        pad[(size_t)b*2*SEQ + SEQ + p*PLEN + t] = ps;
    } else if (t < 64) {
        pad[(size_t)b*2*SEQ + p*PLEN + (t - 32)] = 0.f;
    }
    int ml = lane & 15, kg = lane >> 4;
    s8v ah[2][2];                            // [mt][ks], plain bf16
    #pragma unroll
    for (int mt = 0; mt < 2; ++mt)
        #pragma unroll
        for (int ks = 0; ks < 2; ++ks) {
            #pragma unroll
            for (int j = 0; j < 8; ++j)
                ah[mt][ks][j] = (short)f2bf(u.a.A_T[ks*32 + kg*8 + j][mt*16 + ml]);
        }
    f32x4 accA[8], accB[8];
    #pragma unroll
    for (int nt = 0; nt < 8; ++nt) {
        int fng = w*8 + nt;
        f32x4 acc0 = {}, acc1 = {};
        #pragma unroll
        for (int ks = 0; ks < 2; ++ks) {
            size_t off = ((size_t)(ks*32 + fng)*64 + lane)*8;
            s8v bh = *reinterpret_cast<const s8v*>(rwf + off);
            acc0 = __builtin_amdgcn_mfma_f32_16x16x32_bf16(ah[0][ks], bh, acc0, 0, 0, 0);
            acc1 = __builtin_amdgcn_mfma_f32_16x16x32_bf16(ah[1][ks], bh, acc1, 0, 0, 0);
        }
        float bias = rb[fng*16 + ml];
        #pragma unroll
        for (int r = 0; r < 4; ++r) { acc0[r] += bias; acc1[r] += bias; }
        accA[nt] = acc0; accB[nt] = acc1;
    }
    size_t orow0 = ((size_t)(b*SEQ + p*PLEN))*DMODEL + HALFD;
    #pragma unroll
    for (int mt = 0; mt < 2; ++mt) {
        __syncthreads();
        #pragma unroll
        for (int nt = 0; nt < 8; ++nt) {
            f32x4 a = (mt == 0) ? accA[nt] : accB[nt];
            #pragma unroll
            for (int r = 0; r < 4; ++r)
                u.xpose[kg*4 + r][w*128 + nt*16 + ml] = a[r];
        }
        __syncthreads();
        #pragma unroll
        for (int q = 0; q < 8; ++q) {
            int e = q*256 + t;               // 16 rows x 128 float4
            int rr = e >> 7, c4 = e & 127;
            float4 v = *reinterpret_cast<float4*>(&u.xpose[rr][c4*4]);
            *reinterpret_cast<float4*>(out + orow0 + (size_t)(mt*16 + rr)*DMODEL + c4*4) = v;
        }
    }
}

static const void* by_size(void* const* d_in, const int* in_sizes, int n_in,
                           int want, int fallback) {
    for (int i = 0; i < n_in; ++i) if (in_sizes[i] == want) return d_in[i];
    return d_in[fallback];
}

extern "C" void kernel_launch(void* const* d_in, const int* in_sizes, int n_in,
                              void* d_out, int out_size, void* d_ws, size_t ws_size,
                              hipStream_t stream) {
    const float* src  = (const float*)by_size(d_in, in_sizes, n_in, NB*SEQ*DMODEL, 0);
    const float* pool = (const float*)by_size(d_in, in_sizes, n_in, PNUM*PLEN, 1);
    const float* fw   = (const float*)by_size(d_in, in_sizes, n_in, KDIM*SIM, 2);
    const float* fb   = (const float*)by_size(d_in, in_sizes, n_in, SIM, 3);
    const float* rw   = (const float*)by_size(d_in, in_sizes, n_in, SIM*HALFD, 4);
    const float* rb   = (const float*)by_size(d_in, in_sizes, n_in, HALFD, 5);
    const float* gpw  = (const float*)by_size(d_in, in_sizes, n_in, HALFD*10, 6);
    const float* gpb  = (const float*)by_size(d_in, in_sizes, n_in, 10, 7);
    float* out = (float*)d_out;
    float* pad = out + OUT0;

    int nks = (ws_size >= (size_t)(16u << 20)) ? 32 : 8;

    unsigned short* fwT = (unsigned short*)d_ws;                        // 2 MB
    unsigned short* rwf = fwT + (size_t)SIM*KDIM;                       // 64 KB
    u64*   cand  = (u64*)(rwf + (size_t)SIM*HALFD);                     // 256 KB
    float* part  = (float*)(cand + (size_t)NPATCH*8*SIM);               // nks * 256 KB

    hipLaunchKernelGGL(k_pack, dim3(272),          dim3(256), 0, stream, fw, rw, fwT, rwf);
    hipLaunchKernelGGL(k_mid,  dim3(16*nks + 512), dim3(256), 0, stream,
                       src, fwT, pool, gpw, gpb, part, cand, nks);
    hipLaunchKernelGGL(k_out,  dim3(NCOPY + MROWS), dim3(256), 0, stream,
                       part, fb, cand, pool, rwf, rb, src, out, pad, nks);
}